// Round 18
// baseline (1712.296 us; speedup 1.0000x reference)
//
#include <hip/hip_runtime.h>

// Round 18: DECISIVE DIAGNOSTIC. Graded kernel = R16 verbatim (29.0us, absmax 0).
// Probes sized to be un-crowdable from rocprof top-5 (harness fills ~75us):
//   probe_dpp   x64: per step only hi = dpp64_shr1(hi) + lo  -> isolates lone-wave
//                    cross-lane DPP->VALU dependency latency.
//   probe_chain x24: R16 chain on synthesized values, ZERO loads -> chain component.
//   probe_load  x48: R16 load pattern, trivial consume -> gather/memory component.
// All probes: 512 blocks x 128 threads (same shape as real kernel), write d_ws.

constexpr int Bc = 512, Tc = 512, Cc = 128, Lc = 48;
constexpr double DEPS = 1e-7;
constexpr float FNEG = -1e30f;
constexpr float LN2F = 0.69314718055994530942f;

#define DPP_WAVE_SHR1 0x138
#define DPP_WAVE_SHL1 0x130

__device__ __forceinline__ double dpp64_shr1(double x) {
    long long u = __double_as_longlong(x);
    int a = __builtin_amdgcn_update_dpp(0, (int)u,         DPP_WAVE_SHR1, 0xF, 0xF, false);
    int b = __builtin_amdgcn_update_dpp(0, (int)(u >> 32), DPP_WAVE_SHR1, 0xF, 0xF, false);
    return __longlong_as_double(((long long)b << 32) | (unsigned int)a);
}
__device__ __forceinline__ double dpp64_shl1(double x) {
    long long u = __double_as_longlong(x);
    int a = __builtin_amdgcn_update_dpp(0, (int)u,         DPP_WAVE_SHL1, 0xF, 0xF, false);
    int b = __builtin_amdgcn_update_dpp(0, (int)(u >> 32), DPP_WAVE_SHL1, 0xF, 0xF, false);
    return __longlong_as_double(((long long)b << 32) | (unsigned int)a);
}
__device__ __forceinline__ float lae2(float a, float b) {
    float m = fmaxf(a, b);
    float d = fabsf(a - b);
    return m + __log2f(1.0f + __builtin_amdgcn_exp2f(-d));
}
__device__ __forceinline__ float rd63f(float v) {
    return __uint_as_float((unsigned)
        __builtin_amdgcn_readlane(__float_as_uint(v), 63));
}
__device__ __forceinline__ float log2d(double x) {
    if (!(x > 0.0)) return FNEG;
    long long u = __double_as_longlong(x);
    int e = (int)((u >> 52) & 0x7FF);
    if (e == 0) return FNEG;
    double m = __longlong_as_double((u & 0x000FFFFFFFFFFFFFLL) | 0x3FF0000000000000LL);
    return __log2f((float)m) + (float)(e - 1023);
}
__device__ __forceinline__ float synthp(int k, int lane, int rep) {
    unsigned h = (unsigned)k * 2654435761u + (unsigned)lane * 40503u + (unsigned)rep * 97u;
    return __uint_as_float(0x3B800000u | (h & 0x003FFFFFu));  // [2^-8, 2^-7)
}

// ------------------------------------------------------------ graded kernel (R16)
__global__ __launch_bounds__(128)
void ctc_fb_kernel(const int* __restrict__ y_true,
                   const float* __restrict__ y_pred,
                   float* __restrict__ out) {
    const int b = blockIdx.x;
    const int lane = threadIdx.x & 63;
    const int wave = threadIdx.x >> 6;

    const float* yb = y_pred + (size_t)b * Tc * Cc;

    const int lab = (lane < Lc) ? y_true[b * Lc + lane] : (Cc - 1);
    const int labm1 = __builtin_amdgcn_ds_bpermute(((lane + 63) & 63) << 2, lab);
    const bool skip  = (lab != (Cc - 1)) && (lab != labm1);
    const bool validhi = (lane < Lc);
    const bool lane0 = (lane == 0);

    __shared__ double sblo[64], sbhi[64];
    __shared__ int sbc[64];

    double lo = 0.0, hi = 0.0;
    int c = 0;

    auto renorm = [&]() {
        double mx = fmax(lo, hi);
        int eb = (int)((__double_as_longlong(mx) >> 52) & 0x7FF);
        #pragma unroll
        for (int mk = 1; mk < 64; mk <<= 1)
            eb = max(eb, __shfl_xor(eb, mk, 64));
        int e = eb - 1023;
        double sc = __longlong_as_double((long long)(1023 - e) << 52);
        lo *= sc; hi *= sc;
        c += e;
    };

    float praw[16];
    double pb64[16], ph64[16];
    auto batch = [&]() {
        #pragma unroll
        for (int j = 0; j < 16; ++j) {
            pb64[j] = (double)rd63f(praw[j]) + DEPS;
            ph64[j] = validhi ? ((double)praw[j] + DEPS) : 0.0;
        }
    };

    if (wave == 0) {
        auto step = [&](int j) {
            double sh = dpp64_shr1(hi);
            double a3 = skip ? sh : 0.0;
            double nlo = (lo + sh) * pb64[j];
            double nhi = ((hi + lo) + a3) * ph64[j];
            lo = nlo; hi = nhi;
        };
        #pragma unroll
        for (int j = 0; j < 16; ++j) praw[j] = yb[j * Cc + lab];
        {
            batch();
            const float* ybn = yb + (size_t)16 * Cc + lab;
            #pragma unroll
            for (int j = 0; j < 16; ++j) praw[j] = ybn[(size_t)j * Cc];
            lo = lane0 ? pb64[0] : 0.0;
            hi = lane0 ? ph64[0] : 0.0;
            #pragma unroll
            for (int j = 1; j < 16; ++j) step(j);
        }
        #pragma unroll 1
        for (int g = 1; g < 16; ++g) {
            batch();
            if (g < 15) {
                const float* ybn = yb + (size_t)((g + 1) * 16) * Cc + lab;
                #pragma unroll
                for (int j = 0; j < 16; ++j) praw[j] = ybn[(size_t)j * Cc];
            }
            #pragma unroll
            for (int j = 0; j < 16; ++j) step(j);
            if (g & 1) renorm();
        }
    } else {
        auto step = [&](int j) {
            double qlo = lo * pb64[j];
            double qhi = hi * ph64[j];
            double u  = qlo + (skip ? qhi : 0.0);
            double nb = dpp64_shl1(u);
            lo = qlo + qhi;
            hi = qhi + nb;
        };
        lo = (lane == 48) ? 1.0 : 0.0;
        hi = (lane == 47) ? 1.0 : 0.0;
        #pragma unroll
        for (int j = 0; j < 16; ++j) praw[j] = yb[(size_t)(511 - j) * Cc + lab];
        #pragma unroll 1
        for (int g = 0; g < 16; ++g) {
            batch();
            if (g < 15) {
                const float* ybn = yb + lab;
                const int t0 = 511 - (g + 1) * 16;
                #pragma unroll
                for (int j = 0; j < 16; ++j) praw[j] = ybn[(size_t)(t0 - j) * Cc];
            }
            #pragma unroll
            for (int j = 0; j < 16; ++j) step(j);
            if (g & 1) renorm();
        }
        sblo[lane] = lo;
        sbhi[lane] = hi;
        sbc[lane]  = c;
    }

    __syncthreads();

    if (wave == 0) {
        double plo = lo * sblo[lane];
        double phi = hi * sbhi[lane];
        float ctot = (float)(c + sbc[lane]);
        float yl = log2d(plo) + ctot;
        float yh = log2d(phi) + ctot;
        float v = lae2(yl, yh);
        #pragma unroll
        for (int mk = 1; mk < 64; mk <<= 1)
            v = lae2(v, __shfl_xor(v, mk, 64));
        if (lane0) out[b] = -(v * LN2F);
    }
}

// ----------------------------------------------------------------- probe: dpp x64
__global__ __launch_bounds__(128)
void probe_dpp(const int* __restrict__ y_true,
               const float* __restrict__ y_pred,
               float* __restrict__ ws) {
    const int b = blockIdx.x;
    const int lane = threadIdx.x & 63;
    const int wave = threadIdx.x >> 6;
    double lo = 1.0 + (double)lane * 1e-9 + (double)b * 1e-12;
    double hi = 1.0 + (double)lane * 2e-9;
    #pragma unroll 1
    for (int rep = 0; rep < 64; ++rep) {
        lo += (double)rep * 1e-9;
        #pragma unroll 1
        for (int g = 0; g < 16; ++g) {
            #pragma unroll
            for (int j = 0; j < 16; ++j) {
                hi = dpp64_shr1(hi) + lo;   // minimal cross-lane dependent chain
            }
        }
        hi *= 0.001;                         // keep bounded
    }
    if (lane == 0) ws[b * 2 + wave] = (float)hi;
}

// --------------------------------------------------------------- probe: chain x24
__global__ __launch_bounds__(128)
void probe_chain(const int* __restrict__ y_true,
                 const float* __restrict__ y_pred,
                 float* __restrict__ ws) {
    const int b = blockIdx.x;
    const int lane = threadIdx.x & 63;
    const int wave = threadIdx.x >> 6;

    const int lab = (lane < Lc) ? y_true[b * Lc + lane] : (Cc - 1);
    const int labm1 = __builtin_amdgcn_ds_bpermute(((lane + 63) & 63) << 2, lab);
    const bool skip  = (lab != (Cc - 1)) && (lab != labm1);
    const bool validhi = (lane < Lc);
    const bool lane0 = (lane == 0);

    float fres = 0.0f;
    #pragma unroll 1
    for (int rep = 0; rep < 24; ++rep) {
        double lo = 0.0, hi = 0.0;
        int c = 0;
        auto renorm = [&]() {
            double mx = fmax(lo, hi);
            int eb = (int)((__double_as_longlong(mx) >> 52) & 0x7FF);
            #pragma unroll
            for (int mk = 1; mk < 64; mk <<= 1)
                eb = max(eb, __shfl_xor(eb, mk, 64));
            int e = eb - 1023;
            double sc = __longlong_as_double((long long)(1023 - e) << 52);
            lo *= sc; hi *= sc;
            c += e;
        };
        float praw[16];
        double pb64[16], ph64[16];
        auto batch = [&]() {
            #pragma unroll
            for (int j = 0; j < 16; ++j) {
                pb64[j] = (double)rd63f(praw[j]) + DEPS;
                ph64[j] = validhi ? ((double)praw[j] + DEPS) : 0.0;
            }
        };
        auto synth = [&](int g) {
            #pragma unroll
            for (int j = 0; j < 16; ++j) praw[j] = synthp(g * 16 + j, lane, rep);
        };
        if (wave == 0) {
            auto step = [&](int j) {
                double sh = dpp64_shr1(hi);
                double a3 = skip ? sh : 0.0;
                double nlo = (lo + sh) * pb64[j];
                double nhi = ((hi + lo) + a3) * ph64[j];
                lo = nlo; hi = nhi;
            };
            synth(0);
            batch();
            lo = lane0 ? pb64[0] : 0.0;
            hi = lane0 ? ph64[0] : 0.0;
            #pragma unroll
            for (int j = 1; j < 16; ++j) step(j);
            #pragma unroll 1
            for (int g = 1; g < 16; ++g) {
                synth(g);
                batch();
                #pragma unroll
                for (int j = 0; j < 16; ++j) step(j);
                if (g & 1) renorm();
            }
        } else {
            auto step = [&](int j) {
                double qlo = lo * pb64[j];
                double qhi = hi * ph64[j];
                double u  = qlo + (skip ? qhi : 0.0);
                double nb = dpp64_shl1(u);
                lo = qlo + qhi;
                hi = qhi + nb;
            };
            lo = (lane == 48) ? 1.0 : 0.0;
            hi = (lane == 47) ? 1.0 : 0.0;
            #pragma unroll 1
            for (int g = 0; g < 16; ++g) {
                synth(g);
                batch();
                #pragma unroll
                for (int j = 0; j < 16; ++j) step(j);
                if (g & 1) renorm();
            }
        }
        fres += (float)lo + (float)hi + (float)c;
    }
    #pragma unroll
    for (int mk = 1; mk < 64; mk <<= 1) fres += __shfl_xor(fres, mk, 64);
    if (lane == 0) ws[b * 2 + wave] = fres;
}

// ---------------------------------------------------------------- probe: load x48
__global__ __launch_bounds__(128)
void probe_load(const int* __restrict__ y_true,
                const float* __restrict__ y_pred,
                float* __restrict__ ws) {
    const int b = blockIdx.x;
    const int lane = threadIdx.x & 63;
    const int wave = threadIdx.x >> 6;
    const float* yb = y_pred + (size_t)b * Tc * Cc;
    const int lab = (lane < Lc) ? y_true[b * Lc + lane] : (Cc - 1);

    float acc = 0.0f;
    #pragma unroll 1
    for (int rep = 0; rep < 48; ++rep) {
        acc *= 0.5f;
        float praw[16];
        if (wave == 0) {
            #pragma unroll
            for (int j = 0; j < 16; ++j) praw[j] = yb[j * Cc + lab];
            #pragma unroll 1
            for (int g = 0; g < 16; ++g) {
                #pragma unroll
                for (int j = 0; j < 16; ++j) acc += praw[j];
                if (g < 15) {
                    const float* ybn = yb + (size_t)((g + 1) * 16) * Cc + lab;
                    #pragma unroll
                    for (int j = 0; j < 16; ++j) praw[j] = ybn[(size_t)j * Cc];
                }
            }
        } else {
            #pragma unroll
            for (int j = 0; j < 16; ++j) praw[j] = yb[(size_t)(511 - j) * Cc + lab];
            #pragma unroll 1
            for (int g = 0; g < 16; ++g) {
                #pragma unroll
                for (int j = 0; j < 16; ++j) acc += praw[j];
                if (g < 15) {
                    const float* ybn = yb + lab;
                    const int t0 = 511 - (g + 1) * 16;
                    #pragma unroll
                    for (int j = 0; j < 16; ++j) praw[j] = ybn[(size_t)(t0 - j) * Cc];
                }
            }
        }
    }
    #pragma unroll
    for (int mk = 1; mk < 64; mk <<= 1) acc += __shfl_xor(acc, mk, 64);
    if (lane == 0) ws[b * 2 + wave] = acc;
}

extern "C" void kernel_launch(void* const* d_in, const int* in_sizes, int n_in,
                              void* d_out, int out_size, void* d_ws, size_t ws_size,
                              hipStream_t stream) {
    const int* y_true = (const int*)d_in[0];
    const float* y_pred = (const float*)d_in[1];
    float* out = (float*)d_out;
    float* wsf = (float*)d_ws;
    if (ws_size >= 16384) {
        hipLaunchKernelGGL(probe_dpp,   dim3(Bc), dim3(128), 0, stream, y_true, y_pred, wsf);
        hipLaunchKernelGGL(probe_chain, dim3(Bc), dim3(128), 0, stream, y_true, y_pred, wsf + 1024);
        hipLaunchKernelGGL(probe_load,  dim3(Bc), dim3(128), 0, stream, y_true, y_pred, wsf + 2048);
    }
    hipLaunchKernelGGL(ctc_fb_kernel, dim3(Bc), dim3(128), 0, stream,
                       y_true, y_pred, out);
}

// Round 19
// 34.357 us; speedup vs baseline: 49.8377x; 49.8377x over previous
//
#include <hip/hip_runtime.h>

// CTC batch cost, forward-backward split, f32 probability domain, PER-LANE
// power-of-2 scaling (bit-identical math to round 17, absmax 0.0).
// Round-19 change: 4-deep statically-indexed register load pipeline
// (p0..p3, 16 loads each) issued 4 groups ahead -> ~800ns of load cover per
// consume point, so the compiler's counted vmcnt keeps 3 groups in flight
// and the per-group scattered-load latency stall (probe_load: ~20us of the
// 29us total, measured round 18) overlaps with the chain.
// Wave 0: forward alpha_255 (t=0..255). Wave 1: backward beta_255 (t=511..256).
// loglik = log2(sum_s alpha_255[s]*beta_255[s]) + ca + cb.

constexpr int Bc = 512, Tc = 512, Cc = 128, Lc = 48;
constexpr float FEPS = 1e-7f;
constexpr float FNEG = -1e30f;
constexpr float LN2F = 0.69314718055994530942f;
constexpr int CDEAD = -(1 << 28);  // scale of value-dead lanes

#define DPP_WAVE_SHR1 0x138
#define DPP_WAVE_SHL1 0x130

__device__ __forceinline__ float dppf_shr1(float x) {
    return __int_as_float(__builtin_amdgcn_update_dpp(
        0, __float_as_int(x), DPP_WAVE_SHR1, 0xF, 0xF, false));
}
__device__ __forceinline__ float dppf_shl1(float x) {
    return __int_as_float(__builtin_amdgcn_update_dpp(
        0, __float_as_int(x), DPP_WAVE_SHL1, 0xF, 0xF, false));
}
__device__ __forceinline__ int dppi_shr1_self(int c) {
    return __builtin_amdgcn_update_dpp(c, c, DPP_WAVE_SHR1, 0xF, 0xF, false);
}
__device__ __forceinline__ int dppi_shl1_self(int c) {
    return __builtin_amdgcn_update_dpp(c, c, DPP_WAVE_SHL1, 0xF, 0xF, false);
}

__device__ __forceinline__ float lae2(float a, float b) {  // final reduce only
    float m = fmaxf(a, b);
    float d = fabsf(a - b);
    return m + __log2f(1.0f + __builtin_amdgcn_exp2f(-d));
}
__device__ __forceinline__ float rd63f(float v) {
    return __uint_as_float((unsigned)
        __builtin_amdgcn_readlane(__float_as_uint(v), 63));
}

__global__ __launch_bounds__(128)
void ctc_fb_kernel(const int* __restrict__ y_true,
                   const float* __restrict__ y_pred,
                   float* __restrict__ out) {
    const int b = blockIdx.x;
    const int lane = threadIdx.x & 63;
    const int wave = threadIdx.x >> 6;

    const float* yb = y_pred + (size_t)b * Tc * Cc;

    const int lab = (lane < Lc) ? y_true[b * Lc + lane] : (Cc - 1);
    const int labm1 = __builtin_amdgcn_ds_bpermute(((lane + 63) & 63) << 2, lab);
    const bool skip  = (lab != (Cc - 1)) && (lab != labm1);
    const bool validhi = (lane < Lc);
    const bool lane0 = (lane == 0);

    __shared__ float sblo[64], sbhi[64];
    __shared__ int sbc[64];

    float lo = 0.0f, hi = 0.0f;
    int c = CDEAD;

    auto renorm = [&]() {   // lane-local, every 8 steps
        float mx = fmaxf(lo, hi);
        int e = (int)((__float_as_uint(mx) >> 23) & 0xFF) - 127;
        e = (mx > 0.0f) ? e : 0;
        lo = ldexpf(lo, -e);
        hi = ldexpf(hi, -e);
        c += e;
    };

    float p0[16], p1[16], p2[16], p3[16];   // 4-deep pipeline, static indexing
    float pbf[16], phf[16];

    auto batchv = [&](float (&pr)[16]) {
        #pragma unroll
        for (int j = 0; j < 16; ++j) {
            pbf[j] = rd63f(pr[j]) + FEPS;
            phf[j] = validhi ? (pr[j] + FEPS) : 0.0f;
        }
    };

    if (wave == 0) {
        // -------- forward: alpha_255, consume p_0..p_255 --------
        auto step = [&](int j) {
            float sh  = dppf_shr1(hi);
            int   cm1 = dppi_shr1_self(c);
            bool  own_dead = (lo == 0.0f) && (hi == 0.0f);
            int   m  = own_dead ? cm1 : ((c > cm1) ? c : cm1);
            float lov = ldexpf(lo, c - m);
            float hiv = ldexpf(hi, c - m);
            float shv = ldexpf(sh, cm1 - m);
            float a3  = skip ? shv : 0.0f;
            lo = (lov + shv) * pbf[j];
            hi = (hiv + lov + a3) * phf[j];
            c = m;
        };
        auto steps16 = [&]() {
            #pragma unroll
            for (int j = 0; j < 16; ++j) {
                step(j);
                if (j == 7 || j == 15) renorm();
            }
        };
        auto issue = [&](float (&buf)[16], int g) {
            const float* base = yb + (size_t)(g * 16) * Cc + lab;
            #pragma unroll
            for (int j = 0; j < 16; ++j) buf[j] = base[(size_t)j * Cc];
        };
        issue(p0, 0); issue(p1, 1); issue(p2, 2); issue(p3, 3);
        // group 0 (init at t=0)
        batchv(p0); issue(p0, 4);
        lo = lane0 ? pbf[0] : 0.0f;
        hi = lane0 ? phf[0] : 0.0f;
        c  = lane0 ? 0 : CDEAD;
        #pragma unroll
        for (int j = 1; j < 16; ++j) {
            step(j);
            if (j == 7 || j == 15) renorm();
        }
        batchv(p1); issue(p1, 5); steps16();
        batchv(p2); issue(p2, 6); steps16();
        batchv(p3); issue(p3, 7); steps16();
        #pragma unroll 1
        for (int G = 1; G < 4; ++G) {
            const int g = 4 * G;
            batchv(p0); if (g + 4 < 16) issue(p0, g + 4); steps16();
            batchv(p1); if (g + 5 < 16) issue(p1, g + 5); steps16();
            batchv(p2); if (g + 6 < 16) issue(p2, g + 6); steps16();
            batchv(p3); if (g + 7 < 16) issue(p3, g + 7); steps16();
        }
    } else {
        // -------- backward: beta_255, consume p_511..p_256 --------
        auto step = [&](int j) {
            float qlo = lo * pbf[j];
            float qhi = hi * phf[j];
            float u   = qlo + (skip ? qhi : 0.0f);
            float un  = dppf_shl1(u);
            int   cp1 = dppi_shl1_self(c);
            bool  own_dead = (qlo == 0.0f) && (qhi == 0.0f);
            int   m  = own_dead ? cp1 : ((c > cp1) ? c : cp1);
            lo = ldexpf(qlo + qhi, c - m);
            hi = ldexpf(qhi, c - m) + ldexpf(un, cp1 - m);
            c = m;
        };
        auto steps16 = [&]() {
            #pragma unroll
            for (int j = 0; j < 16; ++j) {
                step(j);
                if (j == 7 || j == 15) renorm();
            }
        };
        auto issue = [&](float (&buf)[16], int g) {
            const int t0 = 511 - g * 16;
            const float* base = yb + lab;
            #pragma unroll
            for (int j = 0; j < 16; ++j) buf[j] = base[(size_t)(t0 - j) * Cc];
        };
        lo = (lane == 48) ? 1.0f : 0.0f;
        hi = (lane == 47) ? 1.0f : 0.0f;
        c  = (lane == 47 || lane == 48) ? 0 : CDEAD;
        issue(p0, 0); issue(p1, 1); issue(p2, 2); issue(p3, 3);
        batchv(p0); issue(p0, 4); steps16();
        batchv(p1); issue(p1, 5); steps16();
        batchv(p2); issue(p2, 6); steps16();
        batchv(p3); issue(p3, 7); steps16();
        #pragma unroll 1
        for (int G = 1; G < 4; ++G) {
            const int g = 4 * G;
            batchv(p0); if (g + 4 < 16) issue(p0, g + 4); steps16();
            batchv(p1); if (g + 5 < 16) issue(p1, g + 5); steps16();
            batchv(p2); if (g + 6 < 16) issue(p2, g + 6); steps16();
            batchv(p3); if (g + 7 < 16) issue(p3, g + 7); steps16();
        }
        sblo[lane] = lo;
        sbhi[lane] = hi;
        sbc[lane]  = c;
    }

    __syncthreads();

    if (wave == 0) {
        float blo = sblo[lane], bhi = sbhi[lane];
        float ctot = (float)(c + sbc[lane]);
        float plo = lo * blo;
        float phi = hi * bhi;
        float yl = (plo > 0.0f) ? (__log2f(plo) + ctot) : FNEG;
        float yh = (phi > 0.0f) ? (__log2f(phi) + ctot) : FNEG;
        float v = lae2(yl, yh);
        #pragma unroll
        for (int mk = 1; mk < 64; mk <<= 1)
            v = lae2(v, __shfl_xor(v, mk, 64));
        if (lane0) out[b] = -(v * LN2F);
    }
}

extern "C" void kernel_launch(void* const* d_in, const int* in_sizes, int n_in,
                              void* d_out, int out_size, void* d_ws, size_t ws_size,
                              hipStream_t stream) {
    const int* y_true = (const int*)d_in[0];
    const float* y_pred = (const float*)d_in[1];
    float* out = (float*)d_out;
    hipLaunchKernelGGL(ctc_fb_kernel, dim3(Bc), dim3(128), 0, stream,
                       y_true, y_pred, out);
}

// Round 20
// 32.944 us; speedup vs baseline: 51.9760x; 1.0429x over previous
//
#include <hip/hip_runtime.h>

// CTC batch cost — producer/consumer wave specialization.
// 4 waves/block (1 batch item): w0 = fwd chain consumer, w1 = bwd chain
// consumer (R17 math verbatim: f32 prob domain, per-lane pow2 scale, absmax 0),
// w2 = fwd producer, w3 = bwd producer. Producers gather p[t][lab] with
// global_load_lds (per-lane scattered SOURCE, uniform LDS dest + lane*4) into
// a [2][8][16][64] f32 LDS ring; publication via counted inline-asm vmcnt
// (FIFO retire) + relaxed LDS flags. No barriers in the loop -> no forced
// vmcnt(0) drains; load latency lives in producer waves, concurrent with the
// consumers' serial chains.

constexpr int Bc = 512, Tc = 512, Cc = 128, Lc = 48;
constexpr float FEPS = 1e-7f;
constexpr float FNEG = -1e30f;
constexpr float LN2F = 0.69314718055994530942f;
constexpr int CDEAD = -(1 << 28);
constexpr int NG = 16;      // 16-step groups per direction
constexpr int RD = 8;       // ring depth (groups)

#define DPP_WAVE_SHR1 0x138
#define DPP_WAVE_SHL1 0x130
#define WG __HIP_MEMORY_SCOPE_WORKGROUP

__device__ __forceinline__ float dppf_shr1(float x) {
    return __int_as_float(__builtin_amdgcn_update_dpp(
        0, __float_as_int(x), DPP_WAVE_SHR1, 0xF, 0xF, false));
}
__device__ __forceinline__ float dppf_shl1(float x) {
    return __int_as_float(__builtin_amdgcn_update_dpp(
        0, __float_as_int(x), DPP_WAVE_SHL1, 0xF, 0xF, false));
}
__device__ __forceinline__ int dppi_shr1_self(int c) {
    return __builtin_amdgcn_update_dpp(c, c, DPP_WAVE_SHR1, 0xF, 0xF, false);
}
__device__ __forceinline__ int dppi_shl1_self(int c) {
    return __builtin_amdgcn_update_dpp(c, c, DPP_WAVE_SHL1, 0xF, 0xF, false);
}
__device__ __forceinline__ float lae2(float a, float b) {
    float m = fmaxf(a, b);
    float d = fabsf(a - b);
    return m + __log2f(1.0f + __builtin_amdgcn_exp2f(-d));
}
__device__ __forceinline__ float rd63f(float v) {
    return __uint_as_float((unsigned)
        __builtin_amdgcn_readlane(__float_as_uint(v), 63));
}

typedef const __attribute__((address_space(1))) void* gptr_t;
typedef __attribute__((address_space(3))) void* lptr_t;
__device__ __forceinline__ void gload(const float* g, float* l) {
    __builtin_amdgcn_global_load_lds((gptr_t)g, (lptr_t)l, 4, 0, 0);
}

__global__ __launch_bounds__(256)
void ctc_pc_kernel(const int* __restrict__ y_true,
                   const float* __restrict__ y_pred,
                   float* __restrict__ out) {
    const int b = blockIdx.x;
    const int tid = threadIdx.x;
    const int lane = tid & 63;
    const int wid = tid >> 6;          // 0,1 consumers; 2,3 producers

    __shared__ float ring[2][RD][16][64];   // 64 KB
    __shared__ int ready[2], done[2];
    __shared__ float sblo[64], sbhi[64];
    __shared__ int sbc[64];

    const float* yb = y_pred + (size_t)b * Tc * Cc;
    const int lab = (lane < Lc) ? y_true[b * Lc + lane] : (Cc - 1);

    if (tid == 0) { ready[0] = ready[1] = 0; done[0] = done[1] = 0; }
    __syncthreads();   // flags visible before pipeline starts

    if (wid >= 2) {
        // ------------------------- producer (dir = wid-2) -------------------
        const int d = wid - 2;
        #pragma unroll 1
        for (int g = 0; g < NG; ++g) {
            if (g >= RD) {   // don't overwrite a slot the consumer still reads
                while (__hip_atomic_load(&done[d], __ATOMIC_RELAXED, WG) < g - (RD - 1))
                    __builtin_amdgcn_s_sleep(1);
            }
            float* lb = &ring[d][g & (RD - 1)][0][0];
            const int t0 = d ? (511 - g * 16) : (g * 16);
            #pragma unroll
            for (int j = 0; j < 16; ++j) {
                const int t = d ? (t0 - j) : (t0 + j);
                gload(yb + (size_t)t * Cc + lab, lb + j * 64);
            }
            if (g >= 3) {   // groups <= g-3 retired once <=48 loads outstanding
                asm volatile("s_waitcnt vmcnt(48)" ::: "memory");
                __builtin_amdgcn_sched_barrier(0);
                if (lane == 0)
                    __hip_atomic_store(&ready[d], g - 2, __ATOMIC_RELAXED, WG);
                __builtin_amdgcn_sched_barrier(0);
            }
        }
        asm volatile("s_waitcnt vmcnt(32)" ::: "memory");
        __builtin_amdgcn_sched_barrier(0);
        if (lane == 0) __hip_atomic_store(&ready[d], NG - 2, __ATOMIC_RELAXED, WG);
        asm volatile("s_waitcnt vmcnt(16)" ::: "memory");
        __builtin_amdgcn_sched_barrier(0);
        if (lane == 0) __hip_atomic_store(&ready[d], NG - 1, __ATOMIC_RELAXED, WG);
        asm volatile("s_waitcnt vmcnt(0)" ::: "memory");
        __builtin_amdgcn_sched_barrier(0);
        if (lane == 0) __hip_atomic_store(&ready[d], NG, __ATOMIC_RELAXED, WG);
    } else {
        // ------------------------- consumer (dir = wid) ---------------------
        const int dir = wid;
        const int labm1 = __builtin_amdgcn_ds_bpermute(((lane + 63) & 63) << 2, lab);
        const bool skip = (lab != (Cc - 1)) && (lab != labm1);
        const bool validhi = (lane < Lc);
        const bool lane0 = (lane == 0);

        float lo = 0.0f, hi = 0.0f;
        int c = CDEAD;

        auto renorm = [&]() {
            float mx = fmaxf(lo, hi);
            int e = (int)((__float_as_uint(mx) >> 23) & 0xFF) - 127;
            e = (mx > 0.0f) ? e : 0;
            lo = ldexpf(lo, -e);
            hi = ldexpf(hi, -e);
            c += e;
        };

        float praw[16], pbf[16], phf[16];

        if (dir == 1) {   // beta_511 init
            lo = (lane == 48) ? 1.0f : 0.0f;
            hi = (lane == 47) ? 1.0f : 0.0f;
            c  = (lane == 47 || lane == 48) ? 0 : CDEAD;
        }

        #pragma unroll 1
        for (int g = 0; g < NG; ++g) {
            while (__hip_atomic_load(&ready[dir], __ATOMIC_RELAXED, WG) < g + 1)
                __builtin_amdgcn_s_sleep(1);
            __builtin_amdgcn_sched_barrier(0);
            #pragma unroll
            for (int j = 0; j < 16; ++j) praw[j] = ring[dir][g & (RD - 1)][j][lane];
            #pragma unroll
            for (int j = 0; j < 16; ++j) {
                pbf[j] = rd63f(praw[j]) + FEPS;
                phf[j] = validhi ? (praw[j] + FEPS) : 0.0f;
            }
            if (dir == 0) {
                int j0 = 0;
                if (g == 0) {   // init at t=0
                    lo = lane0 ? pbf[0] : 0.0f;
                    hi = lane0 ? phf[0] : 0.0f;
                    c  = lane0 ? 0 : CDEAD;
                    j0 = 1;
                }
                #pragma unroll
                for (int j = 0; j < 16; ++j) {
                    if (j < j0) continue;
                    float sh  = dppf_shr1(hi);
                    int   cm1 = dppi_shr1_self(c);
                    bool  own_dead = (lo == 0.0f) && (hi == 0.0f);
                    int   m  = own_dead ? cm1 : ((c > cm1) ? c : cm1);
                    float lov = ldexpf(lo, c - m);
                    float hiv = ldexpf(hi, c - m);
                    float shv = ldexpf(sh, cm1 - m);
                    float a3  = skip ? shv : 0.0f;
                    lo = (lov + shv) * pbf[j];
                    hi = (hiv + lov + a3) * phf[j];
                    c = m;
                    if (j == 7 || j == 15) renorm();
                }
            } else {
                #pragma unroll
                for (int j = 0; j < 16; ++j) {
                    float qlo = lo * pbf[j];
                    float qhi = hi * phf[j];
                    float u   = qlo + (skip ? qhi : 0.0f);
                    float un  = dppf_shl1(u);
                    int   cp1 = dppi_shl1_self(c);
                    bool  own_dead = (qlo == 0.0f) && (qhi == 0.0f);
                    int   m  = own_dead ? cp1 : ((c > cp1) ? c : cp1);
                    lo = ldexpf(qlo + qhi, c - m);
                    hi = ldexpf(qhi, c - m) + ldexpf(un, cp1 - m);
                    c = m;
                    if (j == 7 || j == 15) renorm();
                }
            }
            __builtin_amdgcn_sched_barrier(0);
            if (lane == 0)
                __hip_atomic_store(&done[dir], g + 1, __ATOMIC_RELAXED, WG);
        }

        if (dir == 1) {
            sblo[lane] = lo;
            sbhi[lane] = hi;
            sbc[lane]  = c;
        } else {
            // stash fwd state in registers; combine after barrier below
        }
        // fall through to block-wide sync + combine
        __syncthreads();
        if (dir == 0) {
            float blo = sblo[lane], bhi = sbhi[lane];
            float ctot = (float)(c + sbc[lane]);
            float plo = lo * blo;
            float phi = hi * bhi;
            float yl = (plo > 0.0f) ? (__log2f(plo) + ctot) : FNEG;
            float yh = (phi > 0.0f) ? (__log2f(phi) + ctot) : FNEG;
            float v = lae2(yl, yh);
            #pragma unroll
            for (int mk = 1; mk < 64; mk <<= 1)
                v = lae2(v, __shfl_xor(v, mk, 64));
            if (lane0) out[b] = -(v * LN2F);
        }
        return;
    }
    __syncthreads();   // producers join the consumers' final barrier
}

extern "C" void kernel_launch(void* const* d_in, const int* in_sizes, int n_in,
                              void* d_out, int out_size, void* d_ws, size_t ws_size,
                              hipStream_t stream) {
    const int* y_true = (const int*)d_in[0];
    const float* y_pred = (const float*)d_in[1];
    float* out = (float*)d_out;
    hipLaunchKernelGGL(ctc_pc_kernel, dim3(Bc), dim3(256), 0, stream,
                       y_true, y_pred, out);
}